// Round 1
// baseline (70105.060 us; speedup 1.0000x reference)
//
#include <hip/hip_runtime.h>

typedef _Float16 h8 __attribute__((ext_vector_type(8)));
typedef float f4 __attribute__((ext_vector_type(4)));

// ---- workspace layout (bytes) ----
#define OFF_WRZ0 0ull
#define OFF_WN0  6291456ull
#define OFF_WRZ1 9437184ull
#define OFF_WN1  17825792ull
#define OFF_H0BF 22020096ull   // _Float16 [2][64][1024]
#define OFF_H1BF 22282240ull   // _Float16 [2][64][1024]
#define OFF_RH0  22544384ull   // _Float16 [64][1024]
#define OFF_RH1  22675456ull   // _Float16 [64][1024]
#define OFF_H0F  22806528ull   // float [64][1024]
#define OFF_H1F  23068672ull   // float [64][1024]
#define OFF_Z0F  23330816ull   // float [64][1024]
#define OFF_Z1F  23592960ull   // float [64][1024]
#define OFF_BAR  23855104ull   // unsigned [2] (+pad)
#define ZERO_WORDS 458768      // zero H0BF..BAR region (1,835,072 B) as u32

// ---------------- prep: weights fp32->fp16, zero state + barrier ----------------
__global__ __launch_bounds__(256) void prep_kernel(
    const float* __restrict__ wrz0f, const float* __restrict__ wn0f,
    const float* __restrict__ wrz1f, const float* __restrict__ wn1f,
    _Float16* __restrict__ wrz0, _Float16* __restrict__ wn0,
    _Float16* __restrict__ wrz1, _Float16* __restrict__ wn1,
    unsigned* __restrict__ zbase) {
  size_t i = (size_t)blockIdx.x * blockDim.x + threadIdx.x;
  size_t stride = (size_t)gridDim.x * blockDim.x;
  for (size_t k = i; k < 2048ull * 1536ull; k += stride) wrz0[k] = (_Float16)wrz0f[k];
  for (size_t k = i; k < 1024ull * 1536ull; k += stride) wn0[k]  = (_Float16)wn0f[k];
  for (size_t k = i; k < 2048ull * 2048ull; k += stride) wrz1[k] = (_Float16)wrz1f[k];
  for (size_t k = i; k < 1024ull * 2048ull; k += stride) wn1[k]  = (_Float16)wn1f[k];
  for (size_t k = i; k < (size_t)ZERO_WORDS; k += stride) zbase[k] = 0u;
}

// ---------------- device-scope grid barrier ----------------
__device__ __forceinline__ void grid_barrier(unsigned* bar, unsigned nblocks) {
  __threadfence();            // release: flush this thread's stores device-wide
  __syncthreads();
  if (threadIdx.x == 0) {
    unsigned g = __hip_atomic_load(&bar[1], __ATOMIC_RELAXED, __HIP_MEMORY_SCOPE_AGENT);
    unsigned a = __hip_atomic_fetch_add(&bar[0], 1u, __ATOMIC_ACQ_REL, __HIP_MEMORY_SCOPE_AGENT);
    if (a == nblocks - 1u) {
      __hip_atomic_store(&bar[0], 0u, __ATOMIC_RELAXED, __HIP_MEMORY_SCOPE_AGENT);
      __hip_atomic_store(&bar[1], g + 1u, __ATOMIC_RELEASE, __HIP_MEMORY_SCOPE_AGENT);
    } else {
      while (__hip_atomic_load(&bar[1], __ATOMIC_ACQUIRE, __HIP_MEMORY_SCOPE_AGENT) == g) {
        __builtin_amdgcn_s_sleep(1);
      }
    }
  }
  __syncthreads();
  __threadfence();            // acquire: invalidate stale cached lines
}

// ---------------- block GEMM: out[64 x 32] = A[64 x KTOT] * W[32 x KTOT]^T ----------------
// K split across 4 waves; fp32 partials reduced via LDS by caller.
// A = [A0 (first K0 cols) | A1]; A0 fp32 (x) when F32A else fp16.
template<bool F32A, int K0, int KTOT>
__device__ __forceinline__ void gemm_block(const void* __restrict__ A0, int lda0,
                                           const _Float16* __restrict__ A1, int lda1,
                                           const _Float16* __restrict__ Wt,
                                           float* __restrict__ red) {
  constexpr int KW = KTOT / 4;
  const int lane = threadIdx.x & 63;
  const int wave = threadIdx.x >> 6;
  const int rsub = lane & 15;
  const int kg = (lane >> 4) * 8;
  f4 acc[4][2];
#pragma unroll
  for (int m = 0; m < 4; ++m) {
    acc[m][0] = f4{0.f, 0.f, 0.f, 0.f};
    acc[m][1] = f4{0.f, 0.f, 0.f, 0.f};
  }
  const _Float16* w0p = Wt + (size_t)rsub * KTOT + kg;
  const _Float16* w1p = Wt + (size_t)(16 + rsub) * KTOT + kg;
  const int kbeg = wave * KW;
  const int kend = kbeg + KW;
#pragma unroll 4
  for (int k0 = kbeg; k0 < kend; k0 += 32) {
    h8 wf0 = *(const h8*)(w0p + k0);
    h8 wf1 = *(const h8*)(w1p + k0);
#pragma unroll
    for (int m = 0; m < 4; ++m) {
      h8 a;
      const int ar = m * 16 + rsub;
      if (k0 < K0) {
        if constexpr (F32A) {
          const float* p = (const float*)A0 + (size_t)ar * lda0 + k0 + kg;
          float4 f0 = *(const float4*)p;
          float4 f1 = *(const float4*)(p + 4);
          a[0] = (_Float16)f0.x; a[1] = (_Float16)f0.y; a[2] = (_Float16)f0.z; a[3] = (_Float16)f0.w;
          a[4] = (_Float16)f1.x; a[5] = (_Float16)f1.y; a[6] = (_Float16)f1.z; a[7] = (_Float16)f1.w;
        } else {
          a = *(const h8*)((const _Float16*)A0 + (size_t)ar * lda0 + k0 + kg);
        }
      } else {
        a = *(const h8*)(A1 + (size_t)ar * lda1 + (k0 - K0) + kg);
      }
      acc[m][0] = __builtin_amdgcn_mfma_f32_16x16x32_f16(a, wf0, acc[m][0], 0, 0, 0);
      acc[m][1] = __builtin_amdgcn_mfma_f32_16x16x32_f16(a, wf1, acc[m][1], 0, 0, 0);
    }
  }
  // partials -> LDS: red[wave][row][col]
#pragma unroll
  for (int m = 0; m < 4; ++m)
#pragma unroll
    for (int c = 0; c < 2; ++c)
#pragma unroll
      for (int j = 0; j < 4; ++j) {
        int row = m * 16 + (lane >> 4) * 4 + j;
        int col = c * 16 + rsub;
        red[((size_t)wave * 64 + row) * 32 + col] = acc[m][c][j];
      }
  __syncthreads();
}

// r/z gate apply: r -> rh (fp16 r*h), z -> zf (fp32)
__device__ __forceinline__ void reduce_apply_rz(const float* __restrict__ red, int colbase,
    const float* __restrict__ brz, const float* __restrict__ hf,
    _Float16* __restrict__ rh, float* __restrict__ zf) {
  for (int id = threadIdx.x; id < 2048; id += 256) {
    int row = id >> 5, col = id & 31;
    float v = red[row * 32 + col] + red[2048 + row * 32 + col] +
              red[4096 + row * 32 + col] + red[6144 + row * 32 + col];
    int n = colbase + col;
    float s = 1.f / (1.f + expf(-(v + brz[n])));
    if (n < 1024) {
      rh[row * 1024 + n] = (_Float16)(s * hf[row * 1024 + n]);
    } else {
      zf[row * 1024 + n - 1024] = s;
    }
  }
}

// n gate apply + h update (fp32 master + fp16 copy)
__device__ __forceinline__ void reduce_apply_n(const float* __restrict__ red, int colbase,
    const float* __restrict__ bn, const float* __restrict__ zf,
    float* __restrict__ hf, _Float16* __restrict__ hbf) {
  for (int id = threadIdx.x; id < 2048; id += 256) {
    int row = id >> 5, col = id & 31;
    float v = red[row * 32 + col] + red[2048 + row * 32 + col] +
              red[4096 + row * 32 + col] + red[6144 + row * 32 + col];
    int n = colbase + col;
    float nn = tanhf(v + bn[n]);
    float z = zf[row * 1024 + n];
    float h = hf[row * 1024 + n];
    float o = (1.f - z) * nn + z * h;
    hf[row * 1024 + n] = o;
    hbf[row * 1024 + n] = (_Float16)o;
  }
}

// ---------------- persistent GRU kernel ----------------
// blocks 0..63: layer 0 at step t; blocks 64..127: layer 1 at step t-1.
__global__ __launch_bounds__(256) void gru_main(
    const float* __restrict__ x,
    const _Float16* __restrict__ wrz0, const _Float16* __restrict__ wn0,
    const _Float16* __restrict__ wrz1, const _Float16* __restrict__ wn1,
    const float* __restrict__ brz0, const float* __restrict__ bn0,
    const float* __restrict__ brz1, const float* __restrict__ bn1,
    _Float16* __restrict__ h0bf, _Float16* __restrict__ h1bf,
    _Float16* __restrict__ rh0, _Float16* __restrict__ rh1,
    float* __restrict__ h0f, float* __restrict__ h1f,
    float* __restrict__ z0f, float* __restrict__ z1f,
    unsigned* __restrict__ bar) {
  __shared__ float red[4 * 64 * 32];
  const int bid = blockIdx.x;
  for (int t = 0; t <= 512; ++t) {
    // -------- phase 1: rz gates (layer0 @ t  ||  layer1 @ t-1) --------
    if (bid < 64) {
      if (t < 512) {
        const int cb = 32 * bid;
        gemm_block<true, 512, 1536>(x + (size_t)t * 512, 512 * 512,
                                    h0bf + (size_t)((t + 1) & 1) * 65536, 1024,
                                    wrz0 + (size_t)cb * 1536, red);
        reduce_apply_rz(red, cb, brz0, h0f, rh0, z0f);
      }
    } else {
      if (t >= 1) {
        const int cb = 32 * (bid - 64);
        gemm_block<false, 1024, 2048>(h0bf + (size_t)((t - 1) & 1) * 65536, 1024,
                                      h1bf + (size_t)(t & 1) * 65536, 1024,
                                      wrz1 + (size_t)cb * 2048, red);
        reduce_apply_rz(red, cb, brz1, h1f, rh1, z1f);
      }
    }
    grid_barrier(bar, 128);
    // -------- phase 2: n gate + h update (layer0 @ t || layer1 @ t-1) --------
    if (bid < 32) {
      if (t < 512) {
        const int cb = 32 * bid;
        gemm_block<true, 512, 1536>(x + (size_t)t * 512, 512 * 512,
                                    rh0, 1024,
                                    wn0 + (size_t)cb * 1536, red);
        reduce_apply_n(red, cb, bn0, z0f, h0f, h0bf + (size_t)(t & 1) * 65536);
      }
    } else if (bid >= 64 && bid < 96) {
      if (t >= 1) {
        const int cb = 32 * (bid - 64);
        gemm_block<false, 1024, 2048>(h0bf + (size_t)((t - 1) & 1) * 65536, 1024,
                                      rh1, 1024,
                                      wn1 + (size_t)cb * 2048, red);
        reduce_apply_n(red, cb, bn1, z1f, h1f, h1bf + (size_t)((t - 1) & 1) * 65536);
      }
    }
    grid_barrier(bar, 128);
  }
}

// ---------------- final fc: out[64,512] = h1 @ Wfc^T + bfc ----------------
__global__ __launch_bounds__(256) void fc_kernel(const float* __restrict__ h1f,
                                                 const float* __restrict__ wfc,
                                                 const float* __restrict__ bfc,
                                                 float* __restrict__ out) {
  const int bid = blockIdx.x;  // 64 blocks x 8 cols
#pragma unroll
  for (int rep = 0; rep < 2; ++rep) {
    int local = threadIdx.x + rep * 256;
    int b = local >> 3;
    int o = bid * 8 + (local & 7);
    const float4* hp = (const float4*)(h1f + (size_t)b * 1024);
    const float4* wp = (const float4*)(wfc + (size_t)o * 1024);
    float s = 0.f;
#pragma unroll 4
    for (int i2 = 0; i2 < 256; ++i2) {
      float4 hv = hp[i2], wv = wp[i2];
      s += hv.x * wv.x + hv.y * wv.y + hv.z * wv.z + hv.w * wv.w;
    }
    out[(size_t)b * 512 + o] = s + bfc[o];
  }
}

extern "C" void kernel_launch(void* const* d_in, const int* in_sizes, int n_in,
                              void* d_out, int out_size, void* d_ws, size_t ws_size,
                              hipStream_t stream) {
  const float* x    = (const float*)d_in[0];
  const float* Wrz0 = (const float*)d_in[1];
  const float* brz0 = (const float*)d_in[2];
  const float* Wn0  = (const float*)d_in[3];
  const float* bn0  = (const float*)d_in[4];
  const float* Wrz1 = (const float*)d_in[5];
  const float* brz1 = (const float*)d_in[6];
  const float* Wn1  = (const float*)d_in[7];
  const float* bn1  = (const float*)d_in[8];
  const float* Wfc  = (const float*)d_in[9];
  const float* bfc  = (const float*)d_in[10];
  float* out = (float*)d_out;
  char* ws = (char*)d_ws;

  _Float16* wrz0h = (_Float16*)(ws + OFF_WRZ0);
  _Float16* wn0h  = (_Float16*)(ws + OFF_WN0);
  _Float16* wrz1h = (_Float16*)(ws + OFF_WRZ1);
  _Float16* wn1h  = (_Float16*)(ws + OFF_WN1);
  _Float16* h0bf  = (_Float16*)(ws + OFF_H0BF);
  _Float16* h1bf  = (_Float16*)(ws + OFF_H1BF);
  _Float16* rh0   = (_Float16*)(ws + OFF_RH0);
  _Float16* rh1   = (_Float16*)(ws + OFF_RH1);
  float* h0f = (float*)(ws + OFF_H0F);
  float* h1f = (float*)(ws + OFF_H1F);
  float* z0f = (float*)(ws + OFF_Z0F);
  float* z1f = (float*)(ws + OFF_Z1F);
  unsigned* bar = (unsigned*)(ws + OFF_BAR);

  prep_kernel<<<2048, 256, 0, stream>>>(Wrz0, Wn0, Wrz1, Wn1,
                                        wrz0h, wn0h, wrz1h, wn1h,
                                        (unsigned*)(ws + OFF_H0BF));
  gru_main<<<128, 256, 0, stream>>>(x, wrz0h, wn0h, wrz1h, wn1h,
                                    brz0, bn0, brz1, bn1,
                                    h0bf, h1bf, rh0, rh1,
                                    h0f, h1f, z0f, z1f, bar);
  fc_kernel<<<64, 256, 0, stream>>>(h1f, Wfc, bfc, out);
}

// Round 2
// 22188.370 us; speedup vs baseline: 3.1595x; 3.1595x over previous
//
#include <hip/hip_runtime.h>
#include <math.h>

typedef _Float16 h8 __attribute__((ext_vector_type(8)));
typedef float f4 __attribute__((ext_vector_type(4)));

#define H 1024

// ---- workspace layout (bytes) ----
#define OFF_WRZ0 0ull
#define OFF_WN0  6291456ull
#define OFF_WRZ1 9437184ull
#define OFF_WN1  17825792ull
#define OFF_H0BF 22020096ull   // _Float16 [2][64][1024]
#define OFF_H1BF 22282240ull   // _Float16 [2][64][1024]
#define OFF_RH0  22544384ull   // _Float16 [64][1024]
#define OFF_RH1  22675456ull   // _Float16 [64][1024]
#define OFF_H0F  22806528ull   // float [64][1024]
#define OFF_H1F  23068672ull   // float [64][1024]
#define OFF_Z0F  23330816ull   // float [64][1024]
#define OFF_Z1F  23592960ull   // float [64][1024]
#define OFF_CNT  23855104ull   // unsigned long long [4]
#define ZERO_WORDS 458760      // zero H0BF..CNT+32 as u32

// ---------------- LLC-bypass (agent-scope relaxed) helpers ----------------
__device__ __forceinline__ unsigned long long llc_ld64(const void* p) {
  return __hip_atomic_load((const unsigned long long*)p, __ATOMIC_RELAXED, __HIP_MEMORY_SCOPE_AGENT);
}
__device__ __forceinline__ void llc_st64(void* p, unsigned long long v) {
  __hip_atomic_store((unsigned long long*)p, v, __ATOMIC_RELAXED, __HIP_MEMORY_SCOPE_AGENT);
}
__device__ __forceinline__ void llc_st32(void* p, unsigned v) {
  __hip_atomic_store((unsigned*)p, v, __ATOMIC_RELAXED, __HIP_MEMORY_SCOPE_AGENT);
}
__device__ __forceinline__ unsigned long long pack2f(float a, float b) {
  union { float f[2]; unsigned long long u; } x; x.f[0] = a; x.f[1] = b; return x.u;
}
__device__ __forceinline__ void unpack2f(unsigned long long v, float& a, float& b) {
  union { unsigned long long u; float f[2]; } x; x.u = v; a = x.f[0]; b = x.f[1];
}
__device__ __forceinline__ unsigned packh2(float a, float b) {
  union { _Float16 h[2]; unsigned u; } x; x.h[0] = (_Float16)a; x.h[1] = (_Float16)b; return x.u;
}

// ---------------- prep: weights fp32->fp16, zero comm region ----------------
__global__ __launch_bounds__(256) void prep_kernel(
    const float* __restrict__ wrz0f, const float* __restrict__ wn0f,
    const float* __restrict__ wrz1f, const float* __restrict__ wn1f,
    _Float16* __restrict__ wrz0, _Float16* __restrict__ wn0,
    _Float16* __restrict__ wrz1, _Float16* __restrict__ wn1,
    unsigned* __restrict__ zbase) {
  size_t i = (size_t)blockIdx.x * blockDim.x + threadIdx.x;
  size_t stride = (size_t)gridDim.x * blockDim.x;
  for (size_t k = i; k < 2048ull * 1536ull; k += stride) wrz0[k] = (_Float16)wrz0f[k];
  for (size_t k = i; k < 1024ull * 1536ull; k += stride) wn0[k]  = (_Float16)wn0f[k];
  for (size_t k = i; k < 2048ull * 2048ull; k += stride) wrz1[k] = (_Float16)wrz1f[k];
  for (size_t k = i; k < 1024ull * 2048ull; k += stride) wn1[k]  = (_Float16)wn1f[k];
  for (size_t k = i; k < (size_t)ZERO_WORDS; k += stride) zbase[k] = 0u;
}

// ---------------- flag wait/signal (no fences, no cache maintenance) ----------------
__device__ __forceinline__ void wait_ge(unsigned long long* c, unsigned long long tgt) {
  if (threadIdx.x == 0) {
    while (__hip_atomic_load(c, __ATOMIC_RELAXED, __HIP_MEMORY_SCOPE_AGENT) < tgt)
      __builtin_amdgcn_s_sleep(2);
  }
  __syncthreads();
}
// __syncthreads drains each wave's vmcnt(0) before s_barrier -> all bypass stores
// are at LLC before thread 0 increments the flag (release without wbl2).
__device__ __forceinline__ void signal(unsigned long long* c) {
  __syncthreads();
  if (threadIdx.x == 0)
    __hip_atomic_fetch_add(c, 1ull, __ATOMIC_RELAXED, __HIP_MEMORY_SCOPE_AGENT);
}

// ---------------- stage 64x512 fp16 chunk: LLC -> LDS (XOR-swizzled) ----------------
__device__ __forceinline__ void stage_chunk(const _Float16* __restrict__ src, int koff,
                                            _Float16* __restrict__ sA) {
  const int tid = threadIdx.x;
#pragma unroll
  for (int i = 0; i < 8; ++i) {
    int u = tid + (i << 10);            // 0..8191 (8B units)
    int row = u >> 7;                   // 128 units per row
    int c4 = (u & 127) << 2;            // fp16 col in chunk
    unsigned long long v = llc_ld64(src + (size_t)row * H + koff + c4);
    unsigned byt = (((unsigned)row << 10) + ((unsigned)c4 << 1)) ^ (((unsigned)row & 7u) << 4);
    *(unsigned long long*)((char*)sA + byt) = v;
  }
}

// ---------------- GEMM over staged chunk ----------------
// wave wv: kwq=wv&3 covers k [kwq*128, +128); mw=wv>>2 covers rows mw*16..+15.
// wps[c] = W + (colbase + c*16 + rsub)*ldw (lane-adjusted); coff = W k-offset of chunk.
template<int NT>
__device__ __forceinline__ void gemm_sA(const _Float16* __restrict__ sA,
                                        const _Float16* const* wps, int coff, f4* acc) {
  const int lane = threadIdx.x & 63;
  const int wv = threadIdx.x >> 6;
  const int kwq = wv & 3, mw = wv >> 2;
  const int rsub = lane & 15, kg = (lane >> 4) << 3;
  const int r = mw * 16 + rsub;
  const unsigned rb = ((unsigned)r << 10);
  const unsigned swz = ((unsigned)(r & 7) << 4);
#pragma unroll
  for (int k0 = 0; k0 < 128; k0 += 32) {
    int kc = kwq * 128 + k0 + kg;
    h8 a = *(const h8*)((const char*)sA + ((rb + ((unsigned)kc << 1)) ^ swz));
#pragma unroll
    for (int c = 0; c < NT; ++c) {
      h8 wf = *(const h8*)(wps[c] + coff + kc);
      acc[c] = __builtin_amdgcn_mfma_f32_16x16x32_f16(a, wf, acc[c], 0, 0, 0);
    }
  }
}

// x-part GEMM (layer0, K=512, fp32 x converted in-register); fused rz(2 tiles) + n(1 tile)
__device__ __forceinline__ void gemm_x(const float* __restrict__ x, int t,
                                       const _Float16* __restrict__ wr0,
                                       const _Float16* __restrict__ wr1,
                                       const _Float16* __restrict__ wn,
                                       f4* aRZ, f4* aN) {
  const int lane = threadIdx.x & 63;
  const int wv = threadIdx.x >> 6;
  const int kwq = wv & 3, mw = wv >> 2;
  const int rsub = lane & 15, kg = (lane >> 4) << 3;
  const float* xb = x + (size_t)(mw * 16 + rsub) * 262144 + (size_t)t * 512;
#pragma unroll
  for (int k0 = 0; k0 < 128; k0 += 32) {
    int k = kwq * 128 + k0 + kg;
    float4 f0 = *(const float4*)(xb + k);
    float4 f1 = *(const float4*)(xb + k + 4);
    h8 a;
    a[0] = (_Float16)f0.x; a[1] = (_Float16)f0.y; a[2] = (_Float16)f0.z; a[3] = (_Float16)f0.w;
    a[4] = (_Float16)f1.x; a[5] = (_Float16)f1.y; a[6] = (_Float16)f1.z; a[7] = (_Float16)f1.w;
    aRZ[0] = __builtin_amdgcn_mfma_f32_16x16x32_f16(a, *(const h8*)(wr0 + k), aRZ[0], 0, 0, 0);
    aRZ[1] = __builtin_amdgcn_mfma_f32_16x16x32_f16(a, *(const h8*)(wr1 + k), aRZ[1], 0, 0, 0);
    aN[0]  = __builtin_amdgcn_mfma_f32_16x16x32_f16(a, *(const h8*)(wn + k),  aN[0], 0, 0, 0);
  }
}

// dump per-wave partials to LDS red[kw][64][<=32] (stride 33 to dodge bank conflicts)
template<int NT>
__device__ __forceinline__ void red_write(float* __restrict__ red, const f4* acc) {
  const int lane = threadIdx.x & 63, wv = threadIdx.x >> 6;
  const int kwq = wv & 3, mw = wv >> 2;
  const int rsub = lane & 15, rg = lane >> 4;
#pragma unroll
  for (int c = 0; c < NT; ++c)
#pragma unroll
    for (int j = 0; j < 4; ++j)
      red[(size_t)(kwq * 64 + mw * 16 + rg * 4 + j) * 33 + c * 16 + rsub] = acc[c][j];
}

// rz reduce+apply: sigmoid; r-blocks write rh=r*h (fp16), z-blocks write z (f32)
__device__ __forceinline__ void reduce_rz(const float* __restrict__ red, int cb,
    const float* __restrict__ bias, const float* __restrict__ hf,
    _Float16* __restrict__ rh, float* __restrict__ zf) {
  const int tid = threadIdx.x;
  const int row = tid >> 4, cp = (tid & 15) << 1;
  float v0 = 0.f, v1 = 0.f;
#pragma unroll
  for (int q = 0; q < 4; ++q) {
    const float* rr = red + (size_t)(q * 64 + row) * 33 + cp;
    v0 += rr[0]; v1 += rr[1];
  }
  v0 += bias[cb + cp]; v1 += bias[cb + cp + 1];
  float s0 = 1.f / (1.f + expf(-v0));
  float s1 = 1.f / (1.f + expf(-v1));
  if (cb < 1024) {
    float h0v, h1v;
    unpack2f(llc_ld64(hf + (size_t)row * H + cb + cp), h0v, h1v);
    llc_st32(rh + (size_t)row * H + cb + cp, packh2(s0 * h0v, s1 * h1v));
  } else {
    llc_st64(zf + (size_t)row * H + (cb - 1024) + cp, pack2f(s0, s1));
  }
}

// n reduce+apply + h update (f32 master + fp16 copy)
__device__ __forceinline__ void reduce_n(const float* __restrict__ red, int nb,
    const float* __restrict__ bias, const float* __restrict__ zf,
    float* __restrict__ hf, _Float16* __restrict__ hb) {
  const int tid = threadIdx.x;
  if (tid < 512) {
    const int row = tid >> 3, cp = (tid & 7) << 1;
    float v0 = 0.f, v1 = 0.f;
#pragma unroll
    for (int q = 0; q < 4; ++q) {
      const float* rr = red + (size_t)(q * 64 + row) * 33 + cp;
      v0 += rr[0]; v1 += rr[1];
    }
    v0 += bias[nb + cp]; v1 += bias[nb + cp + 1];
    float n0 = tanhf(v0), n1 = tanhf(v1);
    float z0, z1, h0v, h1v;
    unpack2f(llc_ld64(zf + (size_t)row * H + nb + cp), z0, z1);
    unpack2f(llc_ld64(hf + (size_t)row * H + nb + cp), h0v, h1v);
    float o0 = (1.f - z0) * n0 + z0 * h0v;
    float o1 = (1.f - z1) * n1 + z1 * h1v;
    llc_st64(hf + (size_t)row * H + nb + cp, pack2f(o0, o1));
    llc_st32(hb + (size_t)row * H + nb + cp, packh2(o0, o1));
  }
}

// ---------------- persistent GRU kernel ----------------
// cnt[0]=c_rz0, cnt[1]=c_n0, cnt[2]=c_rz1, cnt[3]=c_n1 (monotonic, 64 producers each/step)
__global__ __launch_bounds__(1024) void gru_main(const float* __restrict__ x,
    const _Float16* __restrict__ wrz0, const _Float16* __restrict__ wn0,
    const _Float16* __restrict__ wrz1, const _Float16* __restrict__ wn1,
    const float* __restrict__ brz0, const float* __restrict__ bn0,
    const float* __restrict__ brz1, const float* __restrict__ bn1,
    _Float16* __restrict__ h0bf, _Float16* __restrict__ h1bf,
    _Float16* __restrict__ rh0, _Float16* __restrict__ rh1,
    float* __restrict__ h0f, float* __restrict__ h1f,
    float* __restrict__ z0f, float* __restrict__ z1f,
    unsigned long long* __restrict__ cnt) {
  __shared__ char smem[65536];            // sA (64KB chunk) unioned with red (33.8KB)
  _Float16* sA = (_Float16*)smem;
  float* red = (float*)smem;
  const int bid = blockIdx.x;
  const int rsub = threadIdx.x & 15;

  if (bid < 64) {
    // ---------- layer 0 ----------
    const int cb = bid * 32, nb = bid * 16;
    const _Float16* wpsRZ[2] = { wrz0 + (size_t)(cb + rsub) * 1536,
                                 wrz0 + (size_t)(cb + 16 + rsub) * 1536 };
    const _Float16* wpsN[1] = { wn0 + (size_t)(nb + rsub) * 1536 };
    for (int t = 0; t < 512; ++t) {
      f4 aRZ[2] = { f4{0.f,0.f,0.f,0.f}, f4{0.f,0.f,0.f,0.f} };
      f4 aN[1] = { f4{0.f,0.f,0.f,0.f} };
      // x-partials for rz AND n gates (no dependency -> before any wait)
      gemm_x(x, t, wpsRZ[0], wpsRZ[1], wpsN[0], aRZ, aN);
      // phase A: rz0(t)  (needs h0(t-1))
      wait_ge(&cnt[1], 64ull * (unsigned long long)t);
      const _Float16* h0p = h0bf + (size_t)((t + 1) & 1) * 65536;
#pragma unroll
      for (int ch = 0; ch < 2; ++ch) {
        stage_chunk(h0p, ch * 512, sA);
        __syncthreads();
        gemm_sA<2>(sA, wpsRZ, 512 + ch * 512, aRZ);
        __syncthreads();
      }
      red_write<2>(red, aRZ);
      __syncthreads();
      reduce_rz(red, cb, brz0, h0f, rh0, z0f);
      signal(&cnt[0]);
      // phase B: n0(t)  (needs rh0(t); backpressure: n1(t-2) must be done with h0bf[t&1])
      wait_ge(&cnt[0], 64ull * (unsigned long long)(t + 1));
      if (t >= 1) wait_ge(&cnt[3], 64ull * (unsigned long long)(t - 1));
#pragma unroll
      for (int ch = 0; ch < 2; ++ch) {
        stage_chunk(rh0, ch * 512, sA);
        __syncthreads();
        gemm_sA<1>(sA, wpsN, 512 + ch * 512, aN);
        __syncthreads();
      }
      red_write<1>(red, aN);
      __syncthreads();
      reduce_n(red, nb, bn0, z0f, h0f, h0bf + (size_t)(t & 1) * 65536);
      signal(&cnt[1]);
    }
  } else {
    // ---------- layer 1 (processes step s = t-1) ----------
    const int b = bid - 64;
    const int cb = b * 32, nb = b * 16;
    const _Float16* wps3[3] = { wrz1 + (size_t)(cb + rsub) * 2048,
                                wrz1 + (size_t)(cb + 16 + rsub) * 2048,
                                wn1  + (size_t)(nb + rsub) * 2048 };
    for (int t = 1; t <= 512; ++t) {
      const int s = t - 1;
      f4 acc3[3] = { f4{0.f,0.f,0.f,0.f}, f4{0.f,0.f,0.f,0.f}, f4{0.f,0.f,0.f,0.f} };
      // phase A: rz1(s). h1(s-1)-part first (available since phase B of t-1).
      wait_ge(&cnt[3], 64ull * (unsigned long long)s);
      const _Float16* h1p = h1bf + (size_t)(t & 1) * 65536;
#pragma unroll
      for (int ch = 0; ch < 2; ++ch) {
        stage_chunk(h1p, ch * 512, sA);
        __syncthreads();
        gemm_sA<2>(sA, wps3, 1024 + ch * 512, acc3);
        __syncthreads();
      }
      // h0(s)-part (needs n0(s) done); fuse n1's h0-part (NT=3, same staged data)
      wait_ge(&cnt[1], 64ull * (unsigned long long)t);
      const _Float16* h0p = h0bf + (size_t)((t + 1) & 1) * 65536;
#pragma unroll
      for (int ch = 0; ch < 2; ++ch) {
        stage_chunk(h0p, ch * 512, sA);
        __syncthreads();
        gemm_sA<3>(sA, wps3, ch * 512, acc3);
        __syncthreads();
      }
      red_write<2>(red, acc3);
      __syncthreads();
      reduce_rz(red, cb, brz1, h1f, rh1, z1f);
      signal(&cnt[2]);
      // phase B: n1(s) rh-part (needs rh1(s))
      wait_ge(&cnt[2], 64ull * (unsigned long long)t);
#pragma unroll
      for (int ch = 0; ch < 2; ++ch) {
        stage_chunk(rh1, ch * 512, sA);
        __syncthreads();
        gemm_sA<1>(sA, wps3 + 2, 1024 + ch * 512, acc3 + 2);
        __syncthreads();
      }
      red_write<1>(red, acc3 + 2);
      __syncthreads();
      reduce_n(red, nb, bn1, z1f, h1f, h1bf + (size_t)(s & 1) * 65536);
      signal(&cnt[3]);
    }
  }
}

// ---------------- final fc: out[64,512] = h1 @ Wfc^T + bfc ----------------
__global__ __launch_bounds__(256) void fc_kernel(const float* __restrict__ h1f,
                                                 const float* __restrict__ wfc,
                                                 const float* __restrict__ bfc,
                                                 float* __restrict__ out) {
  const int bid = blockIdx.x;  // 64 blocks x 8 cols
#pragma unroll
  for (int rep = 0; rep < 2; ++rep) {
    int local = threadIdx.x + rep * 256;
    int b = local >> 3;
    int o = bid * 8 + (local & 7);
    const float4* hp = (const float4*)(h1f + (size_t)b * 1024);
    const float4* wp = (const float4*)(wfc + (size_t)o * 1024);
    float s = 0.f;
#pragma unroll 4
    for (int i2 = 0; i2 < 256; ++i2) {
      float4 hv = hp[i2], wv = wp[i2];
      s += hv.x * wv.x + hv.y * wv.y + hv.z * wv.z + hv.w * wv.w;
    }
    out[(size_t)b * 512 + o] = s + bfc[o];
  }
}

extern "C" void kernel_launch(void* const* d_in, const int* in_sizes, int n_in,
                              void* d_out, int out_size, void* d_ws, size_t ws_size,
                              hipStream_t stream) {
  const float* x    = (const float*)d_in[0];
  const float* Wrz0 = (const float*)d_in[1];
  const float* brz0 = (const float*)d_in[2];
  const float* Wn0  = (const float*)d_in[3];
  const float* bn0  = (const float*)d_in[4];
  const float* Wrz1 = (const float*)d_in[5];
  const float* brz1 = (const float*)d_in[6];
  const float* Wn1  = (const float*)d_in[7];
  const float* bn1  = (const float*)d_in[8];
  const float* Wfc  = (const float*)d_in[9];
  const float* bfc  = (const float*)d_in[10];
  float* out = (float*)d_out;
  char* ws = (char*)d_ws;

  _Float16* wrz0h = (_Float16*)(ws + OFF_WRZ0);
  _Float16* wn0h  = (_Float16*)(ws + OFF_WN0);
  _Float16* wrz1h = (_Float16*)(ws + OFF_WRZ1);
  _Float16* wn1h  = (_Float16*)(ws + OFF_WN1);
  _Float16* h0bf  = (_Float16*)(ws + OFF_H0BF);
  _Float16* h1bf  = (_Float16*)(ws + OFF_H1BF);
  _Float16* rh0   = (_Float16*)(ws + OFF_RH0);
  _Float16* rh1   = (_Float16*)(ws + OFF_RH1);
  float* h0f = (float*)(ws + OFF_H0F);
  float* h1f = (float*)(ws + OFF_H1F);
  float* z0f = (float*)(ws + OFF_Z0F);
  float* z1f = (float*)(ws + OFF_Z1F);
  unsigned long long* cnt = (unsigned long long*)(ws + OFF_CNT);

  prep_kernel<<<2048, 256, 0, stream>>>(Wrz0, Wn0, Wrz1, Wn1,
                                        wrz0h, wn0h, wrz1h, wn1h,
                                        (unsigned*)(ws + OFF_H0BF));
  gru_main<<<128, 1024, 0, stream>>>(x, wrz0h, wn0h, wrz1h, wn1h,
                                     brz0, bn0, brz1, bn1,
                                     h0bf, h1bf, rh0, rh1,
                                     h0f, h1f, z0f, z1f, cnt);
  fc_kernel<<<64, 256, 0, stream>>>(h1f, Wfc, bfc, out);
}